// Round 1
// baseline (990.231 us; speedup 1.0000x reference)
//
#include <hip/hip_runtime.h>

// Problem constants (z: [16, 64, 64, 64] f32, codebook: [2048, 64] f32)
#define BATCH   16
#define C_DIM   64
#define HGT     64
#define WID     64
#define HW      4096        // H*W
#define NROWS   65536       // B*H*W
#define N_E     2048
#define N_ELEM  4194304     // B*C*H*W
// Output layout (flat, concatenated in return order):
//   z_q_out: [16,64,64,64] = 4194304 elems | loss: 1 | perplexity: 1 | indices: 65536
#define OUT_ZQ_OFF   0
#define OUT_LOSS_OFF 4194304
#define OUT_PPL_OFF  4194305
#define OUT_IDX_OFF  4194306

// ---------------------------------------------------------------------------
// Kernel A: per-row argmax over inner products with the codebook.
// Block = 256 threads = 4 waves. Block owns 64 rows (lane = row within block).
// Wave w scans codebook quarter [w*512, w*512+512).
//
// R1 change: codebook broadcast moved from the SCALAR path (readfirstlane +
// s_load -> SGPR, which cannot be double-buffered at the 102-SGPR budget and
// serializes on the per-CU scalar pipe -> VALUBusy 40%) to the VECTOR path:
// per-lane float4 loads at a wave-uniform address. The coalescer turns 64
// identical addresses into one L1 line request with broadcast return, and
// vmcnt-based pipelining lets the compiler keep many loads in flight across
// iterations. __launch_bounds__(256,4) caps regs at 128 so load-hoisting
// cannot drop residency below 16 waves/CU.
// ---------------------------------------------------------------------------
__global__ __launch_bounds__(256, 4) void vq_argmax(
    const float* __restrict__ z, const float* __restrict__ cb,
    int* __restrict__ idx, int* __restrict__ counts)
{
    const int tid  = threadIdx.x;
    const int lane = tid & 63;
    const int wv   = tid >> 6;     // 0..3 (wave-uniform in value, divergent to the compiler)
    const int row0 = blockIdx.x * 64;
    const int n    = row0 + lane;
    const int b    = n >> 12;      // n / HW
    const int hw   = n & 4095;     // n % HW

    // z row into registers: z[b][c][hw], stride HW between c's.
    const float* zbase = z + ((size_t)b * C_DIM) * HW + hw;
    float zr[C_DIM];
#pragma unroll
    for (int c = 0; c < C_DIM; ++c) zr[c] = zbase[(size_t)c * HW];

    const int e0 = wv * (N_E / 4);

    float best = -3.4e38f;
    int   bi   = 0;
    for (int e = 0; e < N_E / 4; e += 2) {
        // Two consecutive codebook rows = 512 contiguous bytes; all lanes read
        // the same addresses -> one line request per load, broadcast return.
        const float4* cv = (const float4*)(cb + (size_t)(e0 + e) * C_DIM);
        float a0 = 0.f, a1 = 0.f, a2 = 0.f, a3 = 0.f;
        float b0 = 0.f, b1 = 0.f, b2 = 0.f, b3 = 0.f;
#pragma unroll
        for (int c4 = 0; c4 < C_DIM / 4; ++c4) {
            float4 qa = cv[c4];            // code e
            float4 qb = cv[c4 + 16];       // code e+1
            a0 = fmaf(zr[4 * c4 + 0], qa.x, a0);
            a1 = fmaf(zr[4 * c4 + 1], qa.y, a1);
            a2 = fmaf(zr[4 * c4 + 2], qa.z, a2);
            a3 = fmaf(zr[4 * c4 + 3], qa.w, a3);
            b0 = fmaf(zr[4 * c4 + 0], qb.x, b0);
            b1 = fmaf(zr[4 * c4 + 1], qb.y, b1);
            b2 = fmaf(zr[4 * c4 + 2], qb.z, b2);
            b3 = fmaf(zr[4 * c4 + 3], qb.w, b3);
        }
        float d0 = (a0 + a1) + (a2 + a3);
        float d1 = (b0 + b1) + (b2 + b3);
        // strict > keeps first occurrence (np.argmax semantics)
        if (d0 > best) { best = d0; bi = e0 + e; }
        if (d1 > best) { best = d1; bi = e0 + e + 1; }
    }

    // Merge the 4 waves' partial (best, idx) per row through LDS.
    __shared__ float sbest[4][64];
    __shared__ int   sbi[4][64];
    sbest[wv][lane] = best;
    sbi[wv][lane]   = bi;
    __syncthreads();
    if (tid < 64) {
        float bb = sbest[0][lane];
        int   ii = sbi[0][lane];
#pragma unroll
        for (int w = 1; w < 4; ++w) {
            float ob = sbest[w][lane];
            int   oi = sbi[w][lane];
            if (ob > bb || (ob == bb && oi < ii)) { bb = ob; ii = oi; }
        }
        idx[row0 + lane] = ii;
        atomicAdd(&counts[ii], 1);
    }
}

// ---------------------------------------------------------------------------
// Kernel B: gather z_q = codebook[idx], write straight-through output
// (zp + (z_q - zp)) back in [B,C,H,W] layout, accumulate sum((z_q-zp)^2),
// and emit indices as float32.
// ---------------------------------------------------------------------------
__global__ __launch_bounds__(256) void vq_outputs(
    const float* __restrict__ z, const float* __restrict__ cb,
    const int* __restrict__ idx, float* __restrict__ out,
    float* __restrict__ loss_accum)
{
    const int n  = blockIdx.x * 256 + threadIdx.x;
    const int b  = n >> 12;
    const int hw = n & 4095;
    const int bi = idx[n];
    out[OUT_IDX_OFF + n] = (float)bi;

    const float* zbase  = z   + ((size_t)b * C_DIM) * HW + hw;
    float*       obase  = out + ((size_t)b * C_DIM) * HW + hw;
    const float4* cbv   = (const float4*)(cb + (size_t)bi * C_DIM);

    float lsum = 0.f;
#pragma unroll
    for (int c4 = 0; c4 < C_DIM / 4; ++c4) {
        float4 qv = cbv[c4];
        float z0 = zbase[(size_t)(4 * c4 + 0) * HW];
        float z1 = zbase[(size_t)(4 * c4 + 1) * HW];
        float z2 = zbase[(size_t)(4 * c4 + 2) * HW];
        float z3 = zbase[(size_t)(4 * c4 + 3) * HW];
        float d0 = qv.x - z0, d1 = qv.y - z1, d2 = qv.z - z2, d3 = qv.w - z3;
        lsum += d0 * d0 + d1 * d1 + d2 * d2 + d3 * d3;
        obase[(size_t)(4 * c4 + 0) * HW] = z0 + d0;   // zp + (z_q - zp)
        obase[(size_t)(4 * c4 + 1) * HW] = z1 + d1;
        obase[(size_t)(4 * c4 + 2) * HW] = z2 + d2;
        obase[(size_t)(4 * c4 + 3) * HW] = z3 + d3;
    }

    // block reduction -> one atomic per block
    for (int off = 32; off > 0; off >>= 1) lsum += __shfl_down(lsum, off, 64);
    __shared__ float wsum[4];
    const int lane = threadIdx.x & 63, w = threadIdx.x >> 6;
    if (lane == 0) wsum[w] = lsum;
    __syncthreads();
    if (threadIdx.x == 0)
        atomicAdd(loss_accum, wsum[0] + wsum[1] + wsum[2] + wsum[3]);
}

// ---------------------------------------------------------------------------
// Kernel C: perplexity from histogram + loss finalize. Single block.
// ---------------------------------------------------------------------------
__global__ __launch_bounds__(256) void vq_finalize(
    const int* __restrict__ counts, const float* __restrict__ loss_accum,
    float* __restrict__ out)
{
    float h = 0.f;
    for (int e = threadIdx.x; e < N_E; e += 256) {
        float em = (float)counts[e] * (1.0f / (float)NROWS);
        h -= em * logf(em + 1e-10f);
    }
    for (int off = 32; off > 0; off >>= 1) h += __shfl_down(h, off, 64);
    __shared__ float hs[4];
    const int lane = threadIdx.x & 63, w = threadIdx.x >> 6;
    if (lane == 0) hs[w] = h;
    __syncthreads();
    if (threadIdx.x == 0) {
        float H = hs[0] + hs[1] + hs[2] + hs[3];
        float m = loss_accum[0] * (1.0f / (float)N_ELEM);
        out[OUT_LOSS_OFF] = 0.25f * m + m;   // BETA*mean + mean
        out[OUT_PPL_OFF]  = expf(H);
    }
}

extern "C" void kernel_launch(void* const* d_in, const int* in_sizes, int n_in,
                              void* d_out, int out_size, void* d_ws, size_t ws_size,
                              hipStream_t stream)
{
    const float* z  = (const float*)d_in[0];
    const float* cb = (const float*)d_in[1];
    float* out = (float*)d_out;

    // workspace layout: idx[65536] int | counts[2048] int | loss_accum float
    int*   idx        = (int*)d_ws;
    int*   counts     = (int*)((char*)d_ws + NROWS * sizeof(int));
    float* loss_accum = (float*)((char*)d_ws + NROWS * sizeof(int) + N_E * sizeof(int));

    hipMemsetAsync(counts, 0, N_E * sizeof(int) + sizeof(float), stream);

    vq_argmax<<<NROWS / 64, 256, 0, stream>>>(z, cb, idx, counts);
    vq_outputs<<<NROWS / 256, 256, 0, stream>>>(z, cb, idx, out, loss_accum);
    vq_finalize<<<1, 256, 0, stream>>>(counts, loss_accum, out);
}

// Round 2
// 480.793 us; speedup vs baseline: 2.0596x; 2.0596x over previous
//
#include <hip/hip_runtime.h>

// Problem constants (z: [16, 64, 64, 64] f32, codebook: [2048, 64] f32)
#define C_DIM   64
#define HW      4096        // H*W
#define NROWS   65536       // B*H*W
#define N_E     2048
#define N_ELEM  4194304     // B*C*H*W
// Output layout (flat, concatenated in return order):
//   z_q_out: [16,64,64,64] = 4194304 elems | loss: 1 | perplexity: 1 | indices: 65536
#define OUT_ZQ_OFF   0
#define OUT_LOSS_OFF 4194304
#define OUT_PPL_OFF  4194305
#define OUT_IDX_OFF  4194306

#define TILE_E   64                   // codes per LDS tile
#define NT       (N_E / TILE_E)       // 32 tiles
#define TILE_F4  (TILE_E * C_DIM / 4) // float4 per tile (1024) = 16 KB
#define THR      256

// ---------------------------------------------------------------------------
// Fused kernel: argmax + gather + straight-through write + loss partial.
//
// R2: codebook streamed through LDS (broadcast ds_read_b128), not the scalar
// pipe. R1 post-mortem showed the 353us baseline was scalar-BW bound:
// 1024 blocks x 512KB codebook = 512MB scalar traffic at ~2.4 B/cyc/CU
// = 348us — exactly the measured time. LDS broadcast reads (same-address =
// no-conflict broadcast) replace that stream; codebook VMEM traffic is
// 512MB through L2 (~15us, hidden). Kernel should now be VALU-bound
// (8.6G FMA -> 109us floor).
//
// Block = 256 threads = 4 waves, owns 64 rows (lane = row, same for all
// waves). Tile loop: prefetch tile t+1 to regs / compute tile t from LDS /
// ds_write tile t+1. One barrier per tile; double-buffered 2x16KB.
// Wave w scans codes [t*64 + w*16, +16) -> 4-way merge via LDS at the end.
// Epilogue fused: wave w writes channels [w*16, +16) of z_q_st, loss
// partials via shfl + one atomic per block, indices from the merge step.
// ---------------------------------------------------------------------------
__global__ __launch_bounds__(256, 4) void vq_fused(
    const float* __restrict__ z, const float* __restrict__ cb,
    float* __restrict__ out, int* __restrict__ counts,
    float* __restrict__ loss_accum)
{
    __shared__ float4 lbuf[2][TILE_F4];   // 2 x 16 KB
    __shared__ float  sbest[4][64];
    __shared__ int    sbi[4][64];
    __shared__ int    sidx[64];
    __shared__ float  wsum[4];

    const int tid  = threadIdx.x;
    const int lane = tid & 63;
    const int wv   = tid >> 6;            // 0..3
    const int row0 = blockIdx.x * 64;
    const int n    = row0 + lane;
    const int b    = n >> 12;             // n / HW  (64 rows per block share b)
    const int hw   = n & 4095;            // n % HW

    // z row into registers: z[b][c][hw], stride HW between c's (coalesced per c).
    const float* zbase = z + ((size_t)b * C_DIM) * HW + hw;
    float zr[C_DIM];
#pragma unroll
    for (int c = 0; c < C_DIM; ++c) zr[c] = zbase[(size_t)c * HW];

    const float4* cbv = (const float4*)cb;

    // Prefetch + write tile 0 (each wave-instr moves 1KB dense: lane-contiguous).
    float4 st[4];
#pragma unroll
    for (int j = 0; j < 4; ++j) st[j] = cbv[j * THR + tid];
#pragma unroll
    for (int j = 0; j < 4; ++j) lbuf[0][j * THR + tid] = st[j];

    float best = -3.4e38f;
    int   bi   = 0;

    for (int t = 0; t < NT; ++t) {
        __syncthreads();                  // lbuf[t&1] fully written
        // issue next tile's global loads early; consumed by ds_write below
        if (t + 1 < NT) {
#pragma unroll
            for (int j = 0; j < 4; ++j)
                st[j] = cbv[(size_t)(t + 1) * TILE_F4 + j * THR + tid];
        }

        const float* lb = (const float*)lbuf[t & 1];
        const int ebase = t * TILE_E + wv * (TILE_E / 4);   // 16 codes per wave

#pragma unroll 2
        for (int e = 0; e < TILE_E / 4; e += 2) {
            // two consecutive code rows from LDS; all lanes same address ->
            // hardware broadcast, no bank conflict
            const float4* cv = (const float4*)(lb + (size_t)(wv * (TILE_E / 4) + e) * C_DIM);
            float a0 = 0.f, a1 = 0.f, a2 = 0.f, a3 = 0.f;
            float b0 = 0.f, b1 = 0.f, b2 = 0.f, b3 = 0.f;
#pragma unroll
            for (int c4 = 0; c4 < C_DIM / 4; ++c4) {
                float4 qa = cv[c4];            // code e
                float4 qb = cv[c4 + 16];       // code e+1
                a0 = fmaf(zr[4 * c4 + 0], qa.x, a0);
                a1 = fmaf(zr[4 * c4 + 1], qa.y, a1);
                a2 = fmaf(zr[4 * c4 + 2], qa.z, a2);
                a3 = fmaf(zr[4 * c4 + 3], qa.w, a3);
                b0 = fmaf(zr[4 * c4 + 0], qb.x, b0);
                b1 = fmaf(zr[4 * c4 + 1], qb.y, b1);
                b2 = fmaf(zr[4 * c4 + 2], qb.z, b2);
                b3 = fmaf(zr[4 * c4 + 3], qb.w, b3);
            }
            float d0 = (a0 + a1) + (a2 + a3);
            float d1 = (b0 + b1) + (b2 + b3);
            // strict > keeps first occurrence (np.argmax semantics)
            if (d0 > best) { best = d0; bi = ebase + e; }
            if (d1 > best) { best = d1; bi = ebase + e + 1; }
        }

        // stage tile t+1 into the other buffer (nobody reads it before the
        // barrier at the top of iteration t+1)
        if (t + 1 < NT) {
            const int nb = (t + 1) & 1;
#pragma unroll
            for (int j = 0; j < 4; ++j) lbuf[nb][j * THR + tid] = st[j];
        }
    }

    // Merge the 4 waves' partial (best, idx) per row; broadcast final index.
    sbest[wv][lane] = best;
    sbi[wv][lane]   = bi;
    __syncthreads();
    if (tid < 64) {
        float bb = sbest[0][lane];
        int   ii = sbi[0][lane];
#pragma unroll
        for (int w = 1; w < 4; ++w) {
            float ob = sbest[w][lane];
            int   oi = sbi[w][lane];
            if (ob > bb || (ob == bb && oi < ii)) { bb = ob; ii = oi; }
        }
        sidx[lane] = ii;
        out[OUT_IDX_OFF + row0 + lane] = (float)ii;
        atomicAdd(&counts[ii], 1);
    }
    __syncthreads();

    // Fused epilogue: wave w owns channels [w*16, w*16+16) of this lane's row.
    const int ii = sidx[lane];
    const int c0 = wv * 16;
    const float4* q4 = (const float4*)(cb + (size_t)ii * C_DIM + c0);
    float* obase = out + ((size_t)b * C_DIM) * HW + hw;

    float lsum = 0.f;
#pragma unroll
    for (int k4 = 0; k4 < 4; ++k4) {
        float4 qv = q4[k4];
        const int c = c0 + 4 * k4;
        float d0 = qv.x - zr[c + 0];
        float d1 = qv.y - zr[c + 1];
        float d2 = qv.z - zr[c + 2];
        float d3 = qv.w - zr[c + 3];
        lsum += d0 * d0 + d1 * d1 + d2 * d2 + d3 * d3;
        obase[(size_t)(c + 0) * HW] = zr[c + 0] + d0;   // zp + (z_q - zp), as ref
        obase[(size_t)(c + 1) * HW] = zr[c + 1] + d1;
        obase[(size_t)(c + 2) * HW] = zr[c + 2] + d2;
        obase[(size_t)(c + 3) * HW] = zr[c + 3] + d3;
    }

    // block reduction -> one atomic per block
    for (int off = 32; off > 0; off >>= 1) lsum += __shfl_down(lsum, off, 64);
    if (lane == 0) wsum[wv] = lsum;
    __syncthreads();
    if (tid == 0)
        atomicAdd(loss_accum, wsum[0] + wsum[1] + wsum[2] + wsum[3]);
}

// ---------------------------------------------------------------------------
// Finalize: perplexity from histogram + loss. Single block.
// ---------------------------------------------------------------------------
__global__ __launch_bounds__(256) void vq_finalize(
    const int* __restrict__ counts, const float* __restrict__ loss_accum,
    float* __restrict__ out)
{
    float h = 0.f;
    for (int e = threadIdx.x; e < N_E; e += 256) {
        float em = (float)counts[e] * (1.0f / (float)NROWS);
        h -= em * logf(em + 1e-10f);
    }
    for (int off = 32; off > 0; off >>= 1) h += __shfl_down(h, off, 64);
    __shared__ float hs[4];
    const int lane = threadIdx.x & 63, w = threadIdx.x >> 6;
    if (lane == 0) hs[w] = h;
    __syncthreads();
    if (threadIdx.x == 0) {
        float H = hs[0] + hs[1] + hs[2] + hs[3];
        float m = loss_accum[0] * (1.0f / (float)N_ELEM);
        out[OUT_LOSS_OFF] = 0.25f * m + m;   // BETA*mean + mean
        out[OUT_PPL_OFF]  = expf(H);
    }
}

extern "C" void kernel_launch(void* const* d_in, const int* in_sizes, int n_in,
                              void* d_out, int out_size, void* d_ws, size_t ws_size,
                              hipStream_t stream)
{
    const float* z  = (const float*)d_in[0];
    const float* cb = (const float*)d_in[1];
    float* out = (float*)d_out;

    // workspace layout: counts[2048] int | loss_accum float
    int*   counts     = (int*)d_ws;
    float* loss_accum = (float*)((char*)d_ws + N_E * sizeof(int));

    hipMemsetAsync(counts, 0, N_E * sizeof(int) + sizeof(float), stream);

    vq_fused<<<NROWS / 64, 256, 0, stream>>>(z, cb, out, counts, loss_accum);
    vq_finalize<<<1, 256, 0, stream>>>(counts, loss_accum, out);
}

// Round 3
// 474.171 us; speedup vs baseline: 2.0883x; 1.0140x over previous
//
#include <hip/hip_runtime.h>

// Problem constants (z: [16, 64, 64, 64] f32, codebook: [2048, 64] f32)
#define C_DIM   64
#define HW      4096        // H*W
#define NROWS   65536       // B*H*W
#define N_E     2048
#define N_ELEM  4194304     // B*C*H*W
// Output layout (flat, concatenated in return order):
//   z_q_out: [16,64,64,64] = 4194304 elems | loss: 1 | perplexity: 1 | indices: 65536
#define OUT_ZQ_OFF   0
#define OUT_LOSS_OFF 4194304
#define OUT_PPL_OFF  4194305
#define OUT_IDX_OFF  4194306

#define TILE_E   64                   // codes per LDS tile
#define NT       (N_E / TILE_E)       // 32 tiles
#define TILE_F4  (TILE_E * C_DIM / 4) // float4 per tile (1024) = 16 KB
#define THR      256

// R3: same structure as R2, but the fused epilogue indexes zr[] ONLY with
// compile-time constants (template<int C0> + switch on wave id). R2's
// runtime-indexed zr[wv*16+...] demoted the whole 64-reg z row to scratch
// (rule #20): WRITE_SIZE 340MB (scratch write-through), VALU busy 3x the
// FMA floor. With zr in VGPRs the main loop is register-FMA fed by LDS
// broadcast ds_read_b128 of the codebook.

template <int C0>
__device__ __forceinline__ float epilogue_slice(
    const float (&zr)[C_DIM], const float* __restrict__ cbrow,
    float* __restrict__ obase)
{
    float lsum = 0.f;
#pragma unroll
    for (int k4 = 0; k4 < 4; ++k4) {
        float4 qv = ((const float4*)(cbrow + C0))[k4];
        float d0 = qv.x - zr[C0 + 4 * k4 + 0];
        float d1 = qv.y - zr[C0 + 4 * k4 + 1];
        float d2 = qv.z - zr[C0 + 4 * k4 + 2];
        float d3 = qv.w - zr[C0 + 4 * k4 + 3];
        lsum += d0 * d0 + d1 * d1 + d2 * d2 + d3 * d3;
        obase[(size_t)(C0 + 4 * k4 + 0) * HW] = zr[C0 + 4 * k4 + 0] + d0;
        obase[(size_t)(C0 + 4 * k4 + 1) * HW] = zr[C0 + 4 * k4 + 1] + d1;
        obase[(size_t)(C0 + 4 * k4 + 2) * HW] = zr[C0 + 4 * k4 + 2] + d2;
        obase[(size_t)(C0 + 4 * k4 + 3) * HW] = zr[C0 + 4 * k4 + 3] + d3;
    }
    return lsum;
}

__global__ __launch_bounds__(256, 4) void vq_fused(
    const float* __restrict__ z, const float* __restrict__ cb,
    float* __restrict__ out, int* __restrict__ counts,
    float* __restrict__ loss_accum)
{
    __shared__ float4 lbuf[2][TILE_F4];   // 2 x 16 KB
    __shared__ float  sbest[4][64];
    __shared__ int    sbi[4][64];
    __shared__ int    sidx[64];
    __shared__ float  wsum[4];

    const int tid  = threadIdx.x;
    const int lane = tid & 63;
    const int wv   = tid >> 6;            // 0..3
    const int row0 = blockIdx.x * 64;
    const int n    = row0 + lane;
    const int b    = n >> 12;             // n / HW  (64 rows per block share b)
    const int hw   = n & 4095;            // n % HW

    // z row into registers: z[b][c][hw], stride HW between c's (coalesced per c).
    const float* zbase = z + ((size_t)b * C_DIM) * HW + hw;
    float zr[C_DIM];
#pragma unroll
    for (int c = 0; c < C_DIM; ++c) zr[c] = zbase[(size_t)c * HW];

    const float4* cbv = (const float4*)cb;

    // Prefetch + write tile 0 (each wave-instr moves 1KB dense: lane-contiguous).
    float4 st[4];
#pragma unroll
    for (int j = 0; j < 4; ++j) st[j] = cbv[j * THR + tid];
#pragma unroll
    for (int j = 0; j < 4; ++j) lbuf[0][j * THR + tid] = st[j];

    float best = -3.4e38f;
    int   bi   = 0;

    for (int t = 0; t < NT; ++t) {
        __syncthreads();                  // lbuf[t&1] fully written
        // issue next tile's global loads early; consumed by ds_write below
        if (t + 1 < NT) {
#pragma unroll
            for (int j = 0; j < 4; ++j)
                st[j] = cbv[(size_t)(t + 1) * TILE_F4 + j * THR + tid];
        }

        const float* lb = (const float*)lbuf[t & 1];
        const int ebase = t * TILE_E + wv * (TILE_E / 4);   // 16 codes per wave

#pragma unroll 2
        for (int e = 0; e < TILE_E / 4; e += 2) {
            // two consecutive code rows from LDS; all lanes same address ->
            // hardware broadcast, no bank conflict
            const float4* cv = (const float4*)(lb + (size_t)(wv * (TILE_E / 4) + e) * C_DIM);
            float a0 = 0.f, a1 = 0.f, a2 = 0.f, a3 = 0.f;
            float b0 = 0.f, b1 = 0.f, b2 = 0.f, b3 = 0.f;
#pragma unroll
            for (int c4 = 0; c4 < C_DIM / 4; ++c4) {
                float4 qa = cv[c4];            // code e
                float4 qb = cv[c4 + 16];       // code e+1
                a0 = fmaf(zr[4 * c4 + 0], qa.x, a0);
                a1 = fmaf(zr[4 * c4 + 1], qa.y, a1);
                a2 = fmaf(zr[4 * c4 + 2], qa.z, a2);
                a3 = fmaf(zr[4 * c4 + 3], qa.w, a3);
                b0 = fmaf(zr[4 * c4 + 0], qb.x, b0);
                b1 = fmaf(zr[4 * c4 + 1], qb.y, b1);
                b2 = fmaf(zr[4 * c4 + 2], qb.z, b2);
                b3 = fmaf(zr[4 * c4 + 3], qb.w, b3);
            }
            float d0 = (a0 + a1) + (a2 + a3);
            float d1 = (b0 + b1) + (b2 + b3);
            // strict > keeps first occurrence (np.argmax semantics)
            if (d0 > best) { best = d0; bi = ebase + e; }
            if (d1 > best) { best = d1; bi = ebase + e + 1; }
        }

        // stage tile t+1 into the other buffer (nobody reads it before the
        // barrier at the top of iteration t+1)
        if (t + 1 < NT) {
            const int nb = (t + 1) & 1;
#pragma unroll
            for (int j = 0; j < 4; ++j) lbuf[nb][j * THR + tid] = st[j];
        }
    }

    // Merge the 4 waves' partial (best, idx) per row; broadcast final index.
    sbest[wv][lane] = best;
    sbi[wv][lane]   = bi;
    __syncthreads();
    if (tid < 64) {
        float bb = sbest[0][lane];
        int   ii = sbi[0][lane];
#pragma unroll
        for (int w = 1; w < 4; ++w) {
            float ob = sbest[w][lane];
            int   oi = sbi[w][lane];
            if (ob > bb || (ob == bb && oi < ii)) { bb = ob; ii = oi; }
        }
        sidx[lane] = ii;
        out[OUT_IDX_OFF + row0 + lane] = (float)ii;
        atomicAdd(&counts[ii], 1);
    }
    __syncthreads();

    // Fused epilogue: wave w owns channels [w*16, w*16+16) of this lane's row.
    // All zr indices compile-time via template dispatch (no scratch demotion).
    const int ii = sidx[lane];
    const float* cbrow = cb + (size_t)ii * C_DIM;
    float* obase = out + ((size_t)b * C_DIM) * HW + hw;

    float lsum;
    switch (wv) {
        case 0:  lsum = epilogue_slice<0>(zr, cbrow, obase);  break;
        case 1:  lsum = epilogue_slice<16>(zr, cbrow, obase); break;
        case 2:  lsum = epilogue_slice<32>(zr, cbrow, obase); break;
        default: lsum = epilogue_slice<48>(zr, cbrow, obase); break;
    }

    // block reduction -> one atomic per block
    for (int off = 32; off > 0; off >>= 1) lsum += __shfl_down(lsum, off, 64);
    if (lane == 0) wsum[wv] = lsum;
    __syncthreads();
    if (tid == 0)
        atomicAdd(loss_accum, wsum[0] + wsum[1] + wsum[2] + wsum[3]);
}

// ---------------------------------------------------------------------------
// Finalize: perplexity from histogram + loss. Single block.
// ---------------------------------------------------------------------------
__global__ __launch_bounds__(256) void vq_finalize(
    const int* __restrict__ counts, const float* __restrict__ loss_accum,
    float* __restrict__ out)
{
    float h = 0.f;
    for (int e = threadIdx.x; e < N_E; e += 256) {
        float em = (float)counts[e] * (1.0f / (float)NROWS);
        h -= em * logf(em + 1e-10f);
    }
    for (int off = 32; off > 0; off >>= 1) h += __shfl_down(h, off, 64);
    __shared__ float hs[4];
    const int lane = threadIdx.x & 63, w = threadIdx.x >> 6;
    if (lane == 0) hs[w] = h;
    __syncthreads();
    if (threadIdx.x == 0) {
        float H = hs[0] + hs[1] + hs[2] + hs[3];
        float m = loss_accum[0] * (1.0f / (float)N_ELEM);
        out[OUT_LOSS_OFF] = 0.25f * m + m;   // BETA*mean + mean
        out[OUT_PPL_OFF]  = expf(H);
    }
}

extern "C" void kernel_launch(void* const* d_in, const int* in_sizes, int n_in,
                              void* d_out, int out_size, void* d_ws, size_t ws_size,
                              hipStream_t stream)
{
    const float* z  = (const float*)d_in[0];
    const float* cb = (const float*)d_in[1];
    float* out = (float*)d_out;

    // workspace layout: counts[2048] int | loss_accum float
    int*   counts     = (int*)d_ws;
    float* loss_accum = (float*)((char*)d_ws + N_E * sizeof(int));

    hipMemsetAsync(counts, 0, N_E * sizeof(int) + sizeof(float), stream);

    vq_fused<<<NROWS / 64, 256, 0, stream>>>(z, cb, out, counts, loss_accum);
    vq_finalize<<<1, 256, 0, stream>>>(counts, loss_accum, out);
}

// Round 4
// 174.799 us; speedup vs baseline: 5.6650x; 2.7127x over previous
//
#include <hip/hip_runtime.h>

// Problem constants (z: [16, 64, 64, 64] f32, codebook: [2048, 64] f32)
#define C_DIM   64
#define HW      4096        // H*W
#define NROWS   65536       // B*H*W
#define N_E     2048
#define N_ELEM  4194304     // B*C*H*W
// Output layout (flat): z_q_out 4194304 | loss 1 | perplexity 1 | indices 65536
#define OUT_LOSS_OFF 4194304
#define OUT_PPL_OFF  4194305
#define OUT_IDX_OFF  4194306

#define ROWS_B   128                 // rows per block (4 waves x 32)
#define NTILE    (N_E / 16)          // 128 code tiles of 16 codes
#define TILE_F4  384                 // 6144 B per tile = 3 splits x 2 k2 x 64 lanes x 16B

typedef __attribute__((ext_vector_type(8))) short bf16x8;
typedef __attribute__((ext_vector_type(4))) float f32x4;

// round-to-nearest-even f32 -> bf16 bits
__device__ __forceinline__ unsigned short f2bf(float f) {
    unsigned u = __float_as_uint(f);
    return (unsigned short)((u + 0x7FFFu + ((u >> 16) & 1u)) >> 16);
}
__device__ __forceinline__ float bf2f(unsigned short b) {
    return __uint_as_float(((unsigned)b) << 16);
}

// ---------------------------------------------------------------------------
// Prep: split codebook f32 -> 3 bf16 terms, scattered into MFMA A-fragment
// order: ushort off = ((tile*3 + s)*2 + k2)*512 + lane*8 + i, where
// tile=c>>4, k2=k>>5, lane=((k&31)>>3)*16 + (c&15), i=k&7.
// (A[16 codes x 32 k]: lane holds row=lane&15, k=(lane>>4)*8+i. Any HW
// k-permutation cancels since the z B-frags use the identical mapping.)
// ---------------------------------------------------------------------------
__global__ __launch_bounds__(256) void vq_prep(
    const float* __restrict__ cb, unsigned short* __restrict__ cbp)
{
    const int u = blockIdx.x * 256 + threadIdx.x;   // [0, 131072)
    const int c = u >> 6, k = u & 63;
    const float v = cb[u];                          // cb[c][k], coalesced
    const unsigned short s1 = f2bf(v);
    const float r1 = v - bf2f(s1);
    const unsigned short s2 = f2bf(r1);
    const float r2 = r1 - bf2f(s2);
    const unsigned short s3 = f2bf(r2);
    const int tile = c >> 4, k2 = k >> 5, kk = k & 31;
    const int lane = (kk >> 3) * 16 + (c & 15), i = kk & 7;
    const int base = ((tile * 3 + 0) * 2 + k2) * 512 + lane * 8 + i;
    cbp[base]        = s1;     // s stride = 2*512
    cbp[base + 1024] = s2;
    cbp[base + 2048] = s3;
}

#define M16(A_, B_, C_) __builtin_amdgcn_mfma_f32_16x16x32_bf16((A_), (B_), (C_), 0, 0, 0)

// 8 split-passes (sc,sz): (1,1)(1,2)(2,1)(2,2)(1,3)(3,1)(2,3)(3,2); only (3,3) dropped.
#define PASS8(ACC, NT)                                                         \
    ACC = M16(A[0][0], zf[0][NT][0], ACC); ACC = M16(A[0][1], zf[0][NT][1], ACC); \
    ACC = M16(A[0][0], zf[1][NT][0], ACC); ACC = M16(A[0][1], zf[1][NT][1], ACC); \
    ACC = M16(A[1][0], zf[0][NT][0], ACC); ACC = M16(A[1][1], zf[0][NT][1], ACC); \
    ACC = M16(A[1][0], zf[1][NT][0], ACC); ACC = M16(A[1][1], zf[1][NT][1], ACC); \
    ACC = M16(A[0][0], zf[2][NT][0], ACC); ACC = M16(A[0][1], zf[2][NT][1], ACC); \
    ACC = M16(A[2][0], zf[0][NT][0], ACC); ACC = M16(A[2][1], zf[0][NT][1], ACC); \
    ACC = M16(A[1][0], zf[2][NT][0], ACC); ACC = M16(A[1][1], zf[2][NT][1], ACC); \
    ACC = M16(A[2][0], zf[1][NT][0], ACC); ACC = M16(A[2][1], zf[1][NT][1], ACC);

__global__ __launch_bounds__(256, 2) void vq_mfma(
    const float* __restrict__ z, const float* __restrict__ cb,
    const unsigned short* __restrict__ cbp, float* __restrict__ out,
    int* __restrict__ counts, float* __restrict__ loss_accum)
{
    __shared__ __align__(16) float zs[C_DIM][ROWS_B];   // 32 KB, [channel][row]
    __shared__ float4 cbbuf[2][TILE_F4];                // 12 KB double-buffered A-frags
    __shared__ int    sidx[ROWS_B];
    __shared__ float  wsum[4];

    const int tid  = threadIdx.x;
    const int lane = tid & 63;
    const int wv   = tid >> 6;            // 0..3
    const int l15  = lane & 15, lg = lane >> 4;
    const int row0 = blockIdx.x * ROWS_B; // 128 rows, same b for whole block
    const int b    = row0 >> 12;
    const int hw0  = row0 & 4095;
    const float* zb = z + (size_t)b * C_DIM * HW + hw0;

    // ---- stage z slice [64 ch][128 rows] into LDS (coalesced float4) ----
#pragma unroll
    for (int j = 0; j < 8; ++j) {
        const int u = j * 256 + tid;              // [0,2048) float4 units
        const int c = u >> 5, x4 = u & 31;
        float4 v = *(const float4*)(zb + (size_t)c * HW + x4 * 4);
        *(float4*)&zs[c][x4 * 4] = v;
    }
    // ---- stage codebook tile 0 ----
    const float4* cbp4 = (const float4*)cbp;
    {
        float4 p0 = cbp4[tid];
        cbbuf[0][tid] = p0;
        if (tid < 128) { float4 p1 = cbp4[256 + tid]; cbbuf[0][256 + tid] = p1; }
    }
    __syncthreads();

    // ---- build z B-fragments: 3 splits x 2 ntiles x 2 k-halves (48 VGPR) ----
    bf16x8 zf[3][2][2];
#pragma unroll
    for (int nt = 0; nt < 2; ++nt) {
        const int row_l = wv * 32 + nt * 16 + l15;
#pragma unroll
        for (int k2 = 0; k2 < 2; ++k2) {
#pragma unroll
            for (int i = 0; i < 8; ++i) {
                float v = zs[k2 * 32 + lg * 8 + i][row_l];
                unsigned short s1 = f2bf(v);
                float r1 = v - bf2f(s1);
                unsigned short s2 = f2bf(r1);
                float r2 = r1 - bf2f(s2);
                zf[0][nt][k2][i] = (short)s1;
                zf[1][nt][k2][i] = (short)s2;
                zf[2][nt][k2][i] = (short)f2bf(r2);
            }
        }
    }

    // ---- main loop over 128 code tiles; 1 barrier/tile, dbuf prefetch ----
    float best0 = -3.4e38f, best1 = -3.4e38f;
    int   bi0 = 0, bi1 = 0;
    const f32x4 zero4 = {0.f, 0.f, 0.f, 0.f};

    for (int t = 0; t < NTILE; ++t) {
        float4 q0 = {0,0,0,0}, q1 = {0,0,0,0};
        if (t + 1 < NTILE) {                       // prefetch next tile to regs
            q0 = cbp4[(size_t)(t + 1) * TILE_F4 + tid];
            if (tid < 128) q1 = cbp4[(size_t)(t + 1) * TILE_F4 + 256 + tid];
        }
        // A-frags for this tile from LDS (broadcast-free b128, lane*16B)
        const bf16x8* Ab = (const bf16x8*)&cbbuf[t & 1][0];
        bf16x8 A[3][2];
#pragma unroll
        for (int s = 0; s < 3; ++s)
#pragma unroll
            for (int k2 = 0; k2 < 2; ++k2)
                A[s][k2] = Ab[(s * 2 + k2) * 64 + lane];

        f32x4 acc0 = zero4, acc1 = zero4;
        PASS8(acc0, 0)
        PASS8(acc1, 1)

        // D layout (m89): col=lane&15 = z-row, row=(lane>>4)*4+reg = code
        const int cbase = t * 16 + lg * 4;
#pragma unroll
        for (int r = 0; r < 4; ++r) {
            if (acc0[r] > best0) { best0 = acc0[r]; bi0 = cbase + r; }
            if (acc1[r] > best1) { best1 = acc1[r]; bi1 = cbase + r; }
        }

        if (t + 1 < NTILE) {                        // write other buffer
            cbbuf[(t + 1) & 1][tid] = q0;
            if (tid < 128) cbbuf[(t + 1) & 1][256 + tid] = q1;
        }
        __syncthreads();
    }

    // ---- merge across the 4 lane-groups (codes are strided by lane>>4) ----
#pragma unroll
    for (int off = 16; off <= 32; off <<= 1) {
        float ob = __shfl_xor(best0, off, 64); int oi = __shfl_xor(bi0, off, 64);
        if (ob > best0 || (ob == best0 && oi < bi0)) { best0 = ob; bi0 = oi; }
        ob = __shfl_xor(best1, off, 64); oi = __shfl_xor(bi1, off, 64);
        if (ob > best1 || (ob == best1 && oi < bi1)) { best1 = ob; bi1 = oi; }
    }
    if (lane < 32) {
        const int nt = lane >> 4;
        const int row_l = wv * 32 + lane;          // = wv*32 + nt*16 + l15
        const int ii = (nt == 0) ? bi0 : bi1;
        sidx[row_l] = ii;
        out[OUT_IDX_OFF + row0 + row_l] = (float)ii;
        atomicAdd(&counts[ii], 1);
    }
    __syncthreads();

    // ---- fused epilogue: gather cb[idx], ST-write, loss partial ----
    float lsum = 0.f;
#pragma unroll
    for (int j = 0; j < 8; ++j) {
        const int m = j * 256 + tid;               // [0,2048)
        const int r = m & 127, c4 = m >> 7;
        const float4 q4 = *(const float4*)(cb + (size_t)sidx[r] * C_DIM + c4 * 4);
#pragma unroll
        for (int q = 0; q < 4; ++q) {
            const int c = c4 * 4 + q;
            const float zv = zs[c][r];
            const float qv = (q == 0) ? q4.x : (q == 1) ? q4.y : (q == 2) ? q4.z : q4.w;
            const float d = qv - zv;               // same fp order as reference ST
            lsum += d * d;
            out[(size_t)b * C_DIM * HW + (size_t)c * HW + hw0 + r] = zv + d;
        }
    }
    for (int off = 32; off > 0; off >>= 1) lsum += __shfl_down(lsum, off, 64);
    if (lane == 0) wsum[wv] = lsum;
    __syncthreads();
    if (tid == 0)
        atomicAdd(loss_accum, wsum[0] + wsum[1] + wsum[2] + wsum[3]);
}

// ---------------------------------------------------------------------------
// Finalize: perplexity from histogram + loss. Single block.
// ---------------------------------------------------------------------------
__global__ __launch_bounds__(256) void vq_finalize(
    const int* __restrict__ counts, const float* __restrict__ loss_accum,
    float* __restrict__ out)
{
    float h = 0.f;
    for (int e = threadIdx.x; e < N_E; e += 256) {
        float em = (float)counts[e] * (1.0f / (float)NROWS);
        h -= em * logf(em + 1e-10f);
    }
    for (int off = 32; off > 0; off >>= 1) h += __shfl_down(h, off, 64);
    __shared__ float hs[4];
    const int lane = threadIdx.x & 63, w = threadIdx.x >> 6;
    if (lane == 0) hs[w] = h;
    __syncthreads();
    if (threadIdx.x == 0) {
        float H = hs[0] + hs[1] + hs[2] + hs[3];
        float m = loss_accum[0] * (1.0f / (float)N_ELEM);
        out[OUT_LOSS_OFF] = 0.25f * m + m;   // BETA*mean + mean
        out[OUT_PPL_OFF]  = expf(H);
    }
}

extern "C" void kernel_launch(void* const* d_in, const int* in_sizes, int n_in,
                              void* d_out, int out_size, void* d_ws, size_t ws_size,
                              hipStream_t stream)
{
    const float* z  = (const float*)d_in[0];
    const float* cb = (const float*)d_in[1];
    float* out = (float*)d_out;

    // ws: counts[2048] int (8KB) | loss f32 | pad | cbp bf16 splits (768KB) @16KB
    int*            counts     = (int*)d_ws;
    float*          loss_accum = (float*)((char*)d_ws + N_E * sizeof(int));
    unsigned short* cbp        = (unsigned short*)((char*)d_ws + 16384);

    hipMemsetAsync(counts, 0, N_E * sizeof(int) + sizeof(float), stream);

    vq_prep<<<N_E * C_DIM / 256, 256, 0, stream>>>(cb, cbp);
    vq_mfma<<<NROWS / ROWS_B, 256, 0, stream>>>(z, cb, cbp, out, counts, loss_accum);
    vq_finalize<<<1, 256, 0, stream>>>(counts, loss_accum, out);
}